// Round 16
// baseline (304.978 us; speedup 1.0000x reference)
//
#include <hip/hip_runtime.h>
#include <hip/hip_bf16.h>
#include <math.h>

// Problem constants
#define Bd 32
#define Sd 32
#define Ld 64
#define Ed 128
#define Hd 128
#define MW 65536   // B*S*L tokens
#define MS 1024    // B*S sentences

// ws layout (float offsets)
#define OFF_WFW_W    196608     // 131072 u16: word attn Ww B-frags hi/lo
#define OFF_WFW_S    262144     // 131072 u16: sent attn Ws B-frags hi/lo
#define OFF_W6       327680     // sets 0-3 region holds WFIHS frags (u16); sets 4,5: sentence GRU fp32
#define OFF_BIH_W    622592     // (unused, kept)
#define OFF_BIH_S    623360
#define OFF_BHH_W    624128     // (unused, kept)
#define OFF_BHH_S    624896
#define OFF_WFX      625664     // 196608 u16: word xp w_ih B-frags [dir][half][nt24][q4][l][e]
#define OFF_HW       723968     // 1024 sents x [t64][hilo2][k256] u16 = 33.5M u16
#define OFF_SENTS    17763328   // 1024 x 256
#define OFF_HS       18811904   // 1024 rows x [hilo2][k256] u16 (packed, r29)
#define OFF_WFHH     19086336   // 196608 u16: W_hh MFMA B-frags hi/lo
#define WS_FLOATS    19184640   // 76.7 MB

typedef __attribute__((ext_vector_type(8))) short sh8;
typedef __attribute__((ext_vector_type(4))) float f32x4;
typedef unsigned short u16;
typedef unsigned int u32;

#define GLD  388   // G stride, 8 rows (seqs 0-7, hi+lo pre-summed)
#define XPLD 385   // xp_lds stride (mod 32 = 1 -> banks spread)
#define HPLD 520   // h_pk per-q stride in u16 (q-pad spreads banks)

// Raw workgroup barrier: waits LDS/shfl (lgkmcnt) only, deliberately NOT vmcnt
// (in-flight global stores/gathers stay in flight across the barrier).
__device__ __forceinline__ void barrier_lds_only() {
    asm volatile("s_waitcnt lgkmcnt(0)\n\ts_barrier" ::: "memory");
}

__device__ __forceinline__ float sigmoidf_(float x) {
    return __fdividef(1.0f, 1.0f + __expf(-x));
}
__device__ __forceinline__ float tanhf_(float x) {
    float t = __expf(-2.0f * fabsf(x));
    float r = __fdividef(1.0f - t, 1.0f + t);
    return copysignf(r, x);
}
__device__ __forceinline__ u16 bf16_hi(float f) {
    u32 x = __float_as_uint(f);
    return (u16)((x + 0x7fffu + ((x >> 16) & 1u)) >> 16);
}
__device__ __forceinline__ float bf16_f(u16 u) { return __uint_as_float(((u32)u) << 16); }
__device__ __forceinline__ void bf16_split(float f, u16& hi, u16& lo) {
    hi = bf16_hi(f);
    lo = bf16_hi(f - bf16_f(hi));
}

// ---------------- fused weight prep (1 launch, 4 sections) ----------------
__global__ void prep_all(const float* __restrict__ s_ih_f, const float* __restrict__ s_ih_b,
                         const float* __restrict__ w_ih_f, const float* __restrict__ w_ih_b,
                         const float* __restrict__ w_hh_f, const float* __restrict__ w_hh_b,
                         const float* __restrict__ s_hh_f, const float* __restrict__ s_hh_b,
                         const float* __restrict__ b_ih_f, const float* __restrict__ b_ih_b,
                         const float* __restrict__ sb_ih_f, const float* __restrict__ sb_ih_b,
                         const float* __restrict__ b_hh_f, const float* __restrict__ b_hh_b,
                         const float* __restrict__ sb_hh_f, const float* __restrict__ sb_hh_b,
                         const float* __restrict__ Ww, const float* __restrict__ Ws,
                         float* __restrict__ ws)
{
    const int b = blockIdx.x;
    if (b < 1164) {
        int i = b * 256 + threadIdx.x;
        if (i < 294912) {  // W6 — only sets 4,5 live (sets 0-3 region = WFIHS, section D)
            int set = i / 49152;
            if (set < 4) return;
            int rem = i % 49152;
            int k4 = rem / 1536, r2 = rem % 1536, g = r2 >> 2, sub = r2 & 3;
            const float* w = (set==4) ? s_hh_f : s_hh_b;
            ws[OFF_W6 + i] = w[g*128 + k4*4 + sub];
            return;
        }
        i -= 294912;
        if (i < 768) { ws[OFF_BIH_W + i] = (i<384) ? b_ih_f[i] : b_ih_b[i-384]; return; }
        i -= 768;
        if (i < 768) { ws[OFF_BIH_S + i] = (i<384) ? sb_ih_f[i] : sb_ih_b[i-384]; return; }
        i -= 768;
        if (i < 768) { ws[OFF_BHH_W + i] = (i<384) ? b_hh_f[i] : b_hh_b[i-384]; return; }
        i -= 768;
        if (i < 768) { ws[OFF_BHH_S + i] = (i<384) ? sb_hh_f[i] : sb_hh_b[i-384]; return; }
        return;
    }
    if (b < 1932) {
        // ---- W_hh frags [dir2][half2][nt24][q4][lane64][elem8] ----
        u16* WFo = (u16*)(ws + OFF_WFHH);
        int i = (b - 1164) * 256 + threadIdx.x;   // < 196608
        int within = i % 49152;
        int combo  = i / 49152;      // dir*2 + half
        int half = combo & 1, dir = combo >> 1;
        int nt  = within / 2048;
        int r2  = within % 2048;
        int q   = r2 >> 9;
        int r3  = r2 & 511;
        int l   = r3 >> 3, e = r3 & 7;
        int n = nt*16 + (l & 15);
        int k = q*32 + ((l >> 4) << 3) + e;
        const float* src = dir ? w_hh_b : w_hh_f;
        float v = src[n*128 + k];
        u16 hi = bf16_hi(v);
        WFo[i] = half ? bf16_hi(v - bf16_f(hi)) : hi;
        return;
    }
    if (b < 3724) {
        // ---- attn (Ww,Ws) + word xp (w_ih) frags ----
        u16* WFW_W = (u16*)(ws + OFF_WFW_W);
        u16* WFW_S = (u16*)(ws + OFF_WFW_S);
        u16* WFX   = (u16*)(ws + OFF_WFX);
        int i = (b - 1932) * 256 + threadIdx.x;   // < 458752
        if (i < 262144) {
            int which = i / 131072;       // 0=Ww, 1=Ws
            int w = i % 131072;
            int half = w / 65536;
            int r = w % 65536;
            int nt = r / 4096;
            int r2 = r % 4096;
            int q = r2 / 512;
            int l = (r2 % 512) >> 3, e = r2 & 7;
            int n = nt*16 + (l & 15);
            int k = q*32 + ((l >> 4) << 3) + e;
            const float* src = which ? Ws : Ww;
            float v = src[n*256 + k];
            u16 hi = bf16_hi(v);
            u16 o = half ? bf16_hi(v - bf16_f(hi)) : hi;
            (which ? WFW_S : WFW_W)[w] = o;
            return;
        }
        i -= 262144;
        if (i < 196608) {
            int w = i % 98304;
            int dir = i / 98304;
            int half = w / 49152;
            int r = w % 49152;
            int nt = r / 2048;
            int r2 = r % 2048;
            int q = r2 / 512;
            int l = (r2 % 512) >> 3, e = r2 & 7;
            int n = nt*16 + (l & 15);
            int k = q*32 + ((l >> 4) << 3) + e;
            const float* src = dir ? w_ih_b : w_ih_f;
            float v = src[n*128 + k];
            u16 hi = bf16_hi(v);
            WFX[i] = half ? bf16_hi(v - bf16_f(hi)) : hi;
            return;
        }
        return;
    }
    {
        // ---- section D: WFIHS = s_ih B-frags [dir2][half2][nt24][q8][l64][e8] ----
        u16* WFIHS = (u16*)(ws + OFF_W6);
        int i = (b - 3724) * 256 + threadIdx.x;   // < 393216
        int dir  = i / 196608;
        int w    = i % 196608;
        int half = w / 98304;
        int r    = w % 98304;
        int nt = r / 4096;
        int r2 = r % 4096;
        int q  = r2 / 512;
        int l  = (r2 % 512) >> 3, e = r2 & 7;
        int n = nt*16 + (l & 15);                 // row in [0,384): gate*128 + j
        int k = q*32 + ((l >> 4) << 3) + e;       // k in [0,256)
        const float* src = dir ? s_ih_b : s_ih_f;
        float v = src[n*256 + k];
        u16 hi = bf16_hi(v);
        WFIHS[i] = half ? bf16_hi(v - bf16_f(hi)) : hi;
    }
}

// ---------------- fused word pipeline (r25 form; plateau ~194us) ----------
__global__ __launch_bounds__(768)
void gru_word_full(const int* __restrict__ X, const float* __restrict__ emb,
                   const u16* __restrict__ WFX, const u16* __restrict__ WFHH,
                   const float* __restrict__ b_ih_f, const float* __restrict__ b_ih_b,
                   const float* __restrict__ b_hh_f, const float* __restrict__ b_hh_b,
                   u16* __restrict__ houtp)
{
    const int bx = blockIdx.x;
    const int dir = bx >> 7;
    const int blk = bx & 127;
    const int seq0 = blk * 8;
    const int tid = threadIdx.x;
    const int lane = tid & 63;
    const int wid = tid >> 6;            // 0..11

    __shared__ float xp_lds[64 * XPLD];      // 98560 B (rows = s*8 + tt)
    __shared__ u16 a_pk[8 * 4 * 512];        // 32768 B
    __shared__ float G[8 * GLD];             // 12416 B (hi+lo pre-summed)
    __shared__ u16 h_pk[4 * HPLD];           // 4160 B (hi rows 0-7, lo rows 8-15)
    __shared__ int ids_s[8][64];             // 2048 B

    const int j = tid & 127;
    const int sg = tid >> 7;             // 0..3 gate threads (s = sg, sg+4)
    const bool gthread = tid < 512;
    const float* bih = dir ? b_ih_b : b_ih_f;
    const float* bhh = dir ? b_hh_b : b_hh_f;
    float bhr = 0.f, bhz = 0.f, bhn = 0.f;
    if (gthread) { bhr = bhh[j]; bhz = bhh[128 + j]; bhn = bhh[256 + j]; }

    const u16* WXbase = WFX + (long)dir * 98304;
    const u16* WHbase = WFHH + (long)dir * 98304;
    const int nt0 = wid*2, nt1 = wid*2 + 1;
    const int c0 = nt0*16 + (lane & 15);
    const int c1 = nt1*16 + (lane & 15);
    // gate-thread h_pk write decomposition for k = j
    const int qj = j >> 5, subkj = (j >> 3) & 3, ej = j & 7;

    for (int i = tid; i < 512; i += 768)
        ids_s[i >> 6][i & 63] = X[(long)(seq0 + (i >> 6))*64 + (i & 63)];
    for (int i = tid; i < 4*HPLD; i += 768) h_pk[i] = 0;
    __syncthreads();

    // prologue: stage chunk 0 with all 768 threads (float4 items)
    for (int idx = tid; idx < 2048; idx += 768) {
        int cc2 = idx & 1, rm = (idx >> 1) & 7, subk = (idx >> 4) & 3;
        int q = (idx >> 6) & 3, mfs = idx >> 8;
        int t = dir ? 63 - rm : rm;          // ts = 0*8 + rm
        int kk = q*32 + subk*8 + cc2*4;
        int id = ids_s[mfs][t];
        float4 v = make_float4(0.f, 0.f, 0.f, 0.f);
        if (id != 0) v = *(const float4*)&emb[(long)id*128 + kk];
        u16 h0,l0,h1,l1,h2,l2,h3,l3;
        bf16_split(v.x,h0,l0); bf16_split(v.y,h1,l1);
        bf16_split(v.z,h2,l2); bf16_split(v.w,h3,l3);
        int lh = subk*16 + rm;
        int base = (mfs*4 + q)*512 + lh*8 + cc2*4;
        uint2 whi = make_uint2((u32)h0 | ((u32)h1 << 16), (u32)h2 | ((u32)h3 << 16));
        uint2 wlo = make_uint2((u32)l0 | ((u32)l1 << 16), (u32)l2 | ((u32)l3 << 16));
        *(uint2*)&a_pk[base]      = whi;
        *(uint2*)&a_pk[base + 64] = wlo;
    }
    __syncthreads();

    float hprev0 = 0.f, hprev1 = 0.f;
    for (int c = 0; c < 8; ++c) {
        asm volatile("" ::: "memory");   // no cross-chunk hoisting of weight loads
        // ---- load W_ih frags (this chunk only) ----
        sh8 xh0[4], xl0[4], xh1[4], xl1[4];
#pragma unroll
        for (int q = 0; q < 4; ++q) {
            xh0[q] = *(const sh8*)(WXbase + (nt0*4 + q)*512 + lane*8);
            xl0[q] = *(const sh8*)(WXbase + 49152 + (nt0*4 + q)*512 + lane*8);
            xh1[q] = *(const sh8*)(WXbase + (nt1*4 + q)*512 + lane*8);
            xl1[q] = *(const sh8*)(WXbase + 49152 + (nt1*4 + q)*512 + lane*8);
        }
        const float bv0 = bih[c0], bv1 = bih[c1];
        // ---- xp MFMA (reads a_pk staged during chunk c-1's steps / prologue) ----
#pragma unroll
        for (int mf = 0; mf < 8; ++mf) {
            f32x4 A0 = (f32x4){0.f,0.f,0.f,0.f};
            f32x4 A1 = (f32x4){0.f,0.f,0.f,0.f};
#pragma unroll
            for (int q = 0; q < 4; ++q) {
                sh8 a = *(const sh8*)&a_pk[(mf*4 + q)*512 + lane*8];
                A0 = __builtin_amdgcn_mfma_f32_16x16x32_bf16(a, xh0[q], A0, 0,0,0);
                A0 = __builtin_amdgcn_mfma_f32_16x16x32_bf16(a, xl0[q], A0, 0,0,0);
                A1 = __builtin_amdgcn_mfma_f32_16x16x32_bf16(a, xh1[q], A1, 0,0,0);
                A1 = __builtin_amdgcn_mfma_f32_16x16x32_bf16(a, xl1[q], A1, 0,0,0);
            }
            float g0[4], g1[4];
#pragma unroll
            for (int r = 0; r < 4; ++r) {
                g0[r] = A0[r] + __shfl_xor(A0[r], 32);
                g1[r] = A1[r] + __shfl_xor(A1[r], 32);
            }
            if ((lane >= 32) == (mf & 1)) {
                int row = mf*8 + ((lane >> 4) & 1)*4;
#pragma unroll
                for (int r = 0; r < 4; ++r) {
                    xp_lds[(row+r)*XPLD + c0] = g0[r] + bv0;
                    xp_lds[(row+r)*XPLD + c1] = g1[r] + bv1;
                }
            }
        }
        barrier_lds_only();   // xp written; a_pk free for chunk c+1 restage
        asm volatile("" ::: "memory");
        // ---- load W_hh frags ----
        sh8 wh0[4], wl0[4], wh1[4], wl1[4];
#pragma unroll
        for (int q = 0; q < 4; ++q) {
            wh0[q] = *(const sh8*)(WHbase + (nt0*4 + q)*512 + lane*8);
            wl0[q] = *(const sh8*)(WHbase + 49152 + (nt0*4 + q)*512 + lane*8);
            wh1[q] = *(const sh8*)(WHbase + (nt1*4 + q)*512 + lane*8);
            wl1[q] = *(const sh8*)(WHbase + 49152 + (nt1*4 + q)*512 + lane*8);
        }
        // ---- 8 recurrence steps (+ chunk c+1 staging by waves 8-11) ----
        for (int tt = 0; tt < 8; ++tt) {
            const int ts = c*8 + tt;
            const int t = dir ? 63 - ts : ts;
            // stage-wave prefetch: issue the gather NOW; consume in the gate window
            float4 sv;
            int s_base = 0;
            const bool sv_ok = !gthread && (c < 7);
            if (sv_ok) {
                const int st = tid - 512;            // 0..255
                const int idx = tt*256 + st;
                int cc2 = idx & 1, rm = (idx >> 1) & 7, subk = (idx >> 4) & 3;
                int q = (idx >> 6) & 3, mfs = idx >> 8;
                int ts2 = (c+1)*8 + rm;
                int t2 = dir ? 63 - ts2 : ts2;
                int kk = q*32 + subk*8 + cc2*4;
                int id = ids_s[mfs][t2];
                sv = make_float4(0.f, 0.f, 0.f, 0.f);
                if (id != 0) sv = *(const float4*)&emb[(long)id*128 + kk];
                int lh = subk*16 + rm;
                s_base = (mfs*4 + q)*512 + lh*8 + cc2*4;
            }
            f32x4 acc0 = (f32x4){0.f,0.f,0.f,0.f};
            f32x4 acc1 = (f32x4){0.f,0.f,0.f,0.f};
#pragma unroll
            for (int q = 0; q < 4; ++q) {
                sh8 hp = *(const sh8*)&h_pk[q*HPLD + lane*8];
                acc0 = __builtin_amdgcn_mfma_f32_16x16x32_bf16(hp, wh0[q], acc0, 0,0,0);
                acc0 = __builtin_amdgcn_mfma_f32_16x16x32_bf16(hp, wl0[q], acc0, 0,0,0);
                acc1 = __builtin_amdgcn_mfma_f32_16x16x32_bf16(hp, wh1[q], acc1, 0,0,0);
                acc1 = __builtin_amdgcn_mfma_f32_16x16x32_bf16(hp, wl1[q], acc1, 0,0,0);
            }
            // summed-G: hi row s (lanes 0-31) + lo row s+8 (lanes 32-63) share a reg
            {
                float sg0[4], sg1[4];
#pragma unroll
                for (int r = 0; r < 4; ++r) {
                    sg0[r] = acc0[r] + __shfl_xor(acc0[r], 32);
                    sg1[r] = acc1[r] + __shfl_xor(acc1[r], 32);
                }
                if (lane < 32) {
                    const int col16 = lane & 15;
                    const int row0  = (lane >> 4) << 2;   // 0 or 4
#pragma unroll
                    for (int r = 0; r < 4; ++r) {
                        G[(row0+r)*GLD + nt0*16 + col16] = sg0[r];
                        G[(row0+r)*GLD + nt1*16 + col16] = sg1[r];
                    }
                }
            }
            barrier_lds_only();
            if (gthread) {
#pragma unroll
                for (int si = 0; si < 2; ++si) {
                    const int s = sg + si*4;
                    float gr  = G[s*GLD + j]       + bhr;
                    float gz  = G[s*GLD + 128 + j] + bhz;
                    float gnh = G[s*GLD + 256 + j] + bhn;
                    const float* xrow = &xp_lds[(s*8 + tt)*XPLD];
                    float r  = sigmoidf_(xrow[j] + gr);
                    float z  = sigmoidf_(xrow[128 + j] + gz);
                    float nv = tanhf_(xrow[256 + j] + r * gnh);
                    float hold = si ? hprev1 : hprev0;
                    float hnew = (1.f - z) * nv + z * hold;
                    if (si) hprev1 = hnew; else hprev0 = hnew;
                    u16 hh, hl; bf16_split(hnew, hh, hl);
                    // paired u32 writes: even j handles the hi row pair, odd j the lo
                    u16 ohh = (u16)__shfl_xor((int)hh, 1);
                    u16 ohl = (u16)__shfl_xor((int)hl, 1);
                    const long tbase = ((long)(seq0 + s)*64 + t)*512 + dir*128;
                    if ((j & 1) == 0) {
                        u32 w = (u32)hh | ((u32)ohh << 16);
                        *(u32*)&h_pk[qj*HPLD + (subkj*16 + s)*8 + ej] = w;
                        *(u32*)&houtp[tbase + j] = w;
                    } else {
                        u32 w = (u32)ohl | ((u32)hl << 16);
                        *(u32*)&h_pk[qj*HPLD + (subkj*16 + s + 8)*8 + (ej - 1)] = w;
                        *(u32*)&houtp[tbase + 256 + (j - 1)] = w;
                    }
                }
            } else if (sv_ok) {
                // stage-wave gate window: split the in-flight gather, store to a_pk
                u16 h0,l0,h1,l1,h2,l2,h3,l3;
                bf16_split(sv.x,h0,l0); bf16_split(sv.y,h1,l1);
                bf16_split(sv.z,h2,l2); bf16_split(sv.w,h3,l3);
                uint2 whi = make_uint2((u32)h0 | ((u32)h1 << 16), (u32)h2 | ((u32)h3 << 16));
                uint2 wlo = make_uint2((u32)l0 | ((u32)l1 << 16), (u32)l2 | ((u32)l3 << 16));
                *(uint2*)&a_pk[s_base]      = whi;
                *(uint2*)&a_pk[s_base + 64] = wlo;
            }
            barrier_lds_only();
        }
    }
}

// ---------------- word attention, 4 sentences/block (r30) --------------------------
// r28's weight-amortization extended: 256 blocks (= exactly 1 dispatch round on 256
// CUs) x 4 sentences, streamed as 2 pairs through the same 2-sentence LDS buffers.
// Weights (256KB Ww frags) loaded ONCE per block: chip-wide frag traffic 134->67MB.
// Per-pair body byte-identical to the proven attn_word2. Barrier analysis: pair-1
// staging (writes a_pk) overlaps only pair-0's out-store (reads red) — disjoint;
// all true deps separated by the per-pair barriers.
__global__ __launch_bounds__(1024)
void attn_word4(const float* __restrict__ A, const u16* __restrict__ WF,
                const float* __restrict__ bias, const float* __restrict__ ctx,
                float* __restrict__ outp)
{
    __shared__ u16 a_pk[2][8][8][512];    // 131072 B
    __shared__ float pscore[2][8][8][17]; // 8704 B
    __shared__ float aw[128];             // 512 B
    __shared__ float red[8][256];         // 8192 B
    const int tid = threadIdx.x;
    const int lane = tid & 63;
    const int wid = tid >> 6;   // 0..15

    sh8 bh[8], bl[8];
#pragma unroll
    for (int q = 0; q < 8; ++q) {
        bh[q] = *(const sh8*)(WF + (wid*8 + q)*512 + lane*8);
        bl[q] = *(const sh8*)(WF + 65536 + (wid*8 + q)*512 + lane*8);
    }
    const int colg = wid*16 + (lane & 15);
    const float bwv = bias[colg];
    const float cxv = ctx[colg];

#pragma unroll 1
    for (int pair = 0; pair < 2; ++pair) {
        const int s0 = blockIdx.x * 4 + pair * 2;

        // uint4 staging, 2 sentences (8192 uint4 items)
        {
            const u32* src32 = (const u32*)A + (long)s0 * 16384;
            u32* dst = (u32*)a_pk;
            for (int idx4 = tid; idx4 < 8192; idx4 += 1024) {
                int sidx = idx4 >> 12;
                int idx  = (idx4 & 4095) << 2;
                int mf = idx >> 11, q = (idx >> 8) & 7, l = (idx >> 2) & 63;
                int row16 = l & 15, hilo = row16 >> 3, rm = row16 & 7;
                int t = mf*8 + rm;
                int kb2 = q*16 + (l >> 4)*4;       // (kbase>>1), multiple of 4
                *(uint4*)&dst[(sidx << 14) + idx] =
                    *(const uint4*)&src32[(long)sidx*16384 + (t*2 + hilo)*128 + kb2];
            }
        }
        __syncthreads();

#pragma unroll 1
        for (int sidx = 0; sidx < 2; ++sidx) {
#pragma unroll
            for (int mf = 0; mf < 8; ++mf) {
                f32x4 acc = (f32x4){0.f,0.f,0.f,0.f};
#pragma unroll
                for (int q = 0; q < 8; ++q) {
                    sh8 a = *(const sh8*)&a_pk[sidx][mf][q][lane*8];
                    acc = __builtin_amdgcn_mfma_f32_16x16x32_bf16(a, bh[q], acc, 0,0,0);
                    acc = __builtin_amdgcn_mfma_f32_16x16x32_bf16(a, bl[q], acc, 0,0,0);
                }
                float g[4];
#pragma unroll
                for (int r = 0; r < 4; ++r) g[r] = acc[r] + __shfl_xor(acc[r], 32);
                if ((lane >= 32) == (mf & 1)) {    // half-dedup: each half handles 4 mf
                    float p[4];
#pragma unroll
                    for (int r = 0; r < 4; ++r) p[r] = tanhf_(g[r] + bwv) * cxv;
#pragma unroll
                    for (int r = 0; r < 4; ++r) {
                        p[r] += __shfl_xor(p[r], 1);
                        p[r] += __shfl_xor(p[r], 2);
                        p[r] += __shfl_xor(p[r], 4);
                        p[r] += __shfl_xor(p[r], 8);
                    }
                    if ((lane & 15) == 0) {
#pragma unroll
                        for (int r = 0; r < 4; ++r)
                            pscore[sidx][mf][((lane >> 4) & 1)*4 + r][wid] = p[r];
                    }
                }
            }
        }
        __syncthreads();

        // softmax over 64 per sentence: wave 0 -> sent 0, wave 1 -> sent 1
        if (tid < 128) {
            const int sidx = tid >> 6, lt = tid & 63;
            float sc = 0.f;
#pragma unroll
            for (int w = 0; w < 16; ++w) sc += pscore[sidx][lt >> 3][lt & 7][w];
            float mx = sc;
#pragma unroll
            for (int m = 1; m < 64; m <<= 1) mx = fmaxf(mx, __shfl_xor(mx, m));
            float e = __expf(sc - mx);
            float den = e;
#pragma unroll
            for (int m = 1; m < 64; m <<= 1) den += __shfl_xor(den, m);
            aw[sidx*64 + lt] = __fdividef(e, den);
        }
        __syncthreads();

        // weighted sum: all 1024 threads; tg8 = (sentence, t-group)
        {
            const int tg8 = tid >> 7;          // 0..7
            const int sidx = tg8 >> 2;
            const int tg = tg8 & 3;
            const int dp = (tid & 127) << 1;
            const int q = dp >> 5, lhb = ((dp & 31) >> 3) << 4, e = dp & 7;
            float acc0 = 0.f, acc1 = 0.f;
#pragma unroll
            for (int ii = 0; ii < 16; ++ii) {
                int t = tg*16 + ii;
                int mf = t >> 3, rm = t & 7;
                const u16* base = &a_pk[sidx][mf][q][(lhb | rm)*8 + e];
                u32 hh = *(const u32*)base;
                u32 ll = *(const u32*)(base + 64);
                float h0 = bf16_f((u16)hh) + bf16_f((u16)ll);
                float h1 = bf16_f((u16)(hh >> 16)) + bf16_f((u16)(ll >> 16));
                float w = aw[sidx*64 + t];
                acc0 = fmaf(w, h0, acc0);
                acc1 = fmaf(w, h1, acc1);
            }
            red[tg8][dp] = acc0; red[tg8][dp + 1] = acc1;
        }
        __syncthreads();
        if (tid < 512) {
            const int sidx = tid >> 8, dd = tid & 255;
            outp[(long)(s0 + sidx)*256 + dd] =
                red[sidx*4 + 0][dd] + red[sidx*4 + 1][dd] + red[sidx*4 + 2][dd] + red[sidx*4 + 3][dd];
        }
        // pair-1 staging may start: its a_pk writes conflict with nothing live
        // (pair-0 a_pk readers done at the pool barrier; out-store reads red only).
    }
}

// ---------------- sentence attention + classifier (r29 packed staging) -------------
__global__ __launch_bounds__(1024)
void attn_sent_cls(const u16* __restrict__ A, const u16* __restrict__ WF,
                   const float* __restrict__ bias, const float* __restrict__ ctx,
                   float* __restrict__ outp,
                   const float* __restrict__ Wc, const float* __restrict__ bc)
{
    __shared__ u16 a_pk[8][8][512];    // 64 KB
    __shared__ float pscore[8][8][17];
    __shared__ float aw[64];
    __shared__ float red[4][256];
    __shared__ float docv[2][256];
    const int tid = threadIdx.x;
    const int lane = tid & 63;
    const int wid = tid >> 6;   // 0..15

    sh8 bh[8], bl[8];
#pragma unroll
    for (int q = 0; q < 8; ++q) {
        bh[q] = *(const sh8*)(WF + (wid*8 + q)*512 + lane*8);
        bl[q] = *(const sh8*)(WF + 65536 + (wid*8 + q)*512 + lane*8);
    }
    const int colg = wid*16 + (lane & 15);
    const float bwv = bias[colg];
    const float cxv = ctx[colg];

    // uint4 packed staging (64 rows = 2 docs x 32 sents)
    {
        const u32* src32 = (const u32*)A + (long)blockIdx.x * 16384;
        u32* dst = (u32*)a_pk;
        for (int idx4 = tid; idx4 < 4096; idx4 += 1024) {
            int idx = idx4 << 2;
            int mf = idx >> 11, q = (idx >> 8) & 7, l = (idx >> 2) & 63;
            int row16 = l & 15, hilo = row16 >> 3, rm = row16 & 7;
            int t = mf*8 + rm;
            int kb2 = q*16 + (l >> 4)*4;
            *(uint4*)&dst[idx] = *(const uint4*)&src32[(t*2 + hilo)*128 + kb2];
        }
    }
    __syncthreads();

#pragma unroll
    for (int mf = 0; mf < 8; ++mf) {
        f32x4 acc = (f32x4){0.f,0.f,0.f,0.f};
#pragma unroll
        for (int q = 0; q < 8; ++q) {
            sh8 a = *(const sh8*)&a_pk[mf][q][lane*8];
            acc = __builtin_amdgcn_mfma_f32_16x16x32_bf16(a, bh[q], acc, 0,0,0);
            acc = __builtin_amdgcn_mfma_f32_16x16x32_bf16(a, bl[q], acc, 0,0,0);
        }
        float g[4];
#pragma unroll
        for (int r = 0; r < 4; ++r) g[r] = acc[r] + __shfl_xor(acc[r], 32);
        if ((lane >= 32) == (mf & 1)) {    // half-dedup
            float p[4];
#pragma unroll
            for (int r = 0; r < 4; ++r) p[r] = tanhf_(g[r] + bwv) * cxv;
#pragma unroll
            for (int r = 0; r < 4; ++r) {
                p[r] += __shfl_xor(p[r], 1);
                p[r] += __shfl_xor(p[r], 2);
                p[r] += __shfl_xor(p[r], 4);
                p[r] += __shfl_xor(p[r], 8);
            }
            if ((lane & 15) == 0) {
#pragma unroll
                for (int r = 0; r < 4; ++r)
                    pscore[mf][((lane >> 4) & 1)*4 + r][wid] = p[r];
            }
        }
    }
    __syncthreads();

    // softmax over 32 per sentence group in wave 0
    if (tid < 64) {
        float sc = 0.f;
#pragma unroll
        for (int w = 0; w < 16; ++w) sc += pscore[tid >> 3][tid & 7][w];
        float mx = sc;
#pragma unroll
        for (int m = 1; m < 32; m <<= 1) mx = fmaxf(mx, __shfl_xor(mx, m));
        float e = __expf(sc - mx);
        float den = e;
#pragma unroll
        for (int m = 1; m < 32; m <<= 1) den += __shfl_xor(den, m);
        aw[tid] = __fdividef(e, den);
    }
    __syncthreads();

    if (tid < 512) {
        const int dp = (tid & 127) << 1;
        const int tg = tid >> 7;          // 0..3
        const int q = dp >> 5, lhb = ((dp & 31) >> 3) << 4, e = dp & 7;
        float acc0 = 0.f, acc1 = 0.f;
#pragma unroll
        for (int ii = 0; ii < 16; ++ii) {
            int t = tg*16 + ii;
            int mf = t >> 3, rm = t & 7;
            const u16* base = &a_pk[mf][q][(lhb | rm)*8 + e];
            u32 hh = *(const u32*)base;
            u32 ll = *(const u32*)(base + 64);
            float h0 = bf16_f((u16)hh) + bf16_f((u16)ll);
            float h1 = bf16_f((u16)(hh >> 16)) + bf16_f((u16)(ll >> 16));
            float w = aw[t];
            acc0 = fmaf(w, h0, acc0);
            acc1 = fmaf(w, h1, acc1);
        }
        red[tg][dp] = acc0; red[tg][dp + 1] = acc1;
    }
    __syncthreads();
    // classifier fusion: docv -> logits
    if (tid < 512) {
        int sent = tid >> 8, dd = tid & 255;
        docv[sent][dd] = red[sent*2][dd] + red[sent*2 + 1][dd];
    }
    __syncthreads();
    if (tid < 20) {
        int s = tid / 10, c = tid % 10;
        float acc = bc[c];
        const float4* wp = (const float4*)&Wc[c*256];
        const float4* dv = (const float4*)&docv[s][0];
#pragma unroll 8
        for (int d = 0; d < 64; ++d) {
            float4 a = dv[d], w = wp[d];
            acc = fmaf(a.x, w.x, fmaf(a.y, w.y, fmaf(a.z, w.z, fmaf(a.w, w.w, acc))));
        }
        outp[(blockIdx.x*2 + s)*10 + c] = acc;
    }
}

// ---------------- sentence pipeline: xp MFMA + GRU -> packed u16 h (r29) -----------
__global__ __launch_bounds__(512)
void gru_sent(const float* __restrict__ sents, const u16* __restrict__ WFIHS,
              const float* __restrict__ bih_s, const float4* __restrict__ whh4,
              const float* __restrict__ bhh, u16* __restrict__ houtp)
{
    const int bx = blockIdx.x;
    const int dir = bx >> 5;
    const int doc = bx & 31;
    const int tid = threadIdx.x;
    const int lane = tid & 63;
    const int wid = tid >> 6;            // 0..7

    __shared__ float xp_lds[32 * XPLD];  // 49280 B
    __shared__ u16 a_pk[4 * 8 * 512];    // 32768 B: [mf4][q8][l64][e8]
    __shared__ float h_lds[128];

    for (int i = tid; i < 128; i += 512) h_lds[i] = 0.f;

    // ---- phase 1: stage sents rows -> A-frags ----
    for (int idx = tid; idx < 2048; idx += 512) {
        int cc2 = idx & 1, rm = (idx >> 1) & 7, subk = (idx >> 4) & 3;
        int q = (idx >> 6) & 7, mf = (idx >> 9) & 3;
        int t = mf*8 + rm;
        int kk = q*32 + subk*8 + cc2*4;
        float4 v = *(const float4*)&sents[(long)(doc*32 + t)*256 + kk];
        u16 h0,l0,h1,l1,h2,l2,h3,l3;
        bf16_split(v.x,h0,l0); bf16_split(v.y,h1,l1);
        bf16_split(v.z,h2,l2); bf16_split(v.w,h3,l3);
        int lh = subk*16 + rm;
        int base = (mf*8 + q)*512 + lh*8 + cc2*4;
        uint2 whi = make_uint2((u32)h0 | ((u32)h1 << 16), (u32)h2 | ((u32)h3 << 16));
        uint2 wlo = make_uint2((u32)l0 | ((u32)l1 << 16), (u32)l2 | ((u32)l3 << 16));
        *(uint2*)&a_pk[base]      = whi;
        *(uint2*)&a_pk[base + 64] = wlo;
    }
    barrier_lds_only();

    // ---- phase 2: xp MFMA, wave w -> nt {w, w+8, w+16} ----
    const u16* WFbase = WFIHS + (long)dir * 196608;
#pragma unroll 1
    for (int ni = 0; ni < 3; ++ni) {
        const int nt = wid + ni*8;
        sh8 wh[8], wl[8];
#pragma unroll
        for (int q = 0; q < 8; ++q) {
            wh[q] = *(const sh8*)(WFbase + (nt*8 + q)*512 + lane*8);
            wl[q] = *(const sh8*)(WFbase + 98304 + (nt*8 + q)*512 + lane*8);
        }
        const int col16 = lane & 15;
        const float bv = bih_s[dir*384 + nt*16 + col16];
        f32x4 A0 = (f32x4){0.f,0.f,0.f,0.f};
        f32x4 A1 = (f32x4){0.f,0.f,0.f,0.f};
        f32x4 A2 = (f32x4){0.f,0.f,0.f,0.f};
        f32x4 A3 = (f32x4){0.f,0.f,0.f,0.f};
#pragma unroll
        for (int q = 0; q < 8; ++q) {
            sh8 a0 = *(const sh8*)&a_pk[(0*8 + q)*512 + lane*8];
            sh8 a1 = *(const sh8*)&a_pk[(1*8 + q)*512 + lane*8];
            sh8 a2 = *(const sh8*)&a_pk[(2*8 + q)*512 + lane*8];
            sh8 a3 = *(const sh8*)&a_pk[(3*8 + q)*512 + lane*8];
            A0 = __builtin_amdgcn_mfma_f32_16x16x32_bf16(a0, wh[q], A0, 0,0,0);
            A0 = __builtin_amdgcn_mfma_f32_16x16x32_bf16(a0, wl[q], A0, 0,0,0);
            A1 = __builtin_amdgcn_mfma_f32_16x16x32_bf16(a1, wh[q], A1, 0,0,0);
            A1 = __builtin_amdgcn_mfma_f32_16x16x32_bf16(a1, wl[q], A1, 0,0,0);
            A2 = __builtin_amdgcn_mfma_f32_16x16x32_bf16(a2, wh[q], A2, 0,0,0);
            A2 = __builtin_amdgcn_mfma_f32_16x16x32_bf16(a2, wl[q], A2, 0,0,0);
            A3 = __builtin_amdgcn_mfma_f32_16x16x32_bf16(a3, wh[q], A3, 0,0,0);
            A3 = __builtin_amdgcn_mfma_f32_16x16x32_bf16(a3, wl[q], A3, 0,0,0);
        }
#pragma unroll
        for (int mf = 0; mf < 4; ++mf) {
            f32x4 A = (mf==0) ? A0 : (mf==1) ? A1 : (mf==2) ? A2 : A3;
            float g[4];
#pragma unroll
            for (int r = 0; r < 4; ++r) g[r] = A[r] + __shfl_xor(A[r], 32);
            if ((lane >= 32) == (mf & 1)) {
                int row = mf*8 + ((lane >> 4) & 1)*4;
#pragma unroll
                for (int r = 0; r < 4; ++r)
                    xp_lds[(row+r)*XPLD + nt*16 + col16] = g[r] + bv;
            }
        }
    }
    barrier_lds_only();
    asm volatile("" ::: "memory");   // keep recurrence weight loads below xp phase

    // ---- phase 3: recurrence (full hoisted weights; xp from LDS) ----
    const int kq = tid & 3;
    const int j  = tid >> 2;
    const float4* W = whh4 + (long)dir * 12288;
    const float bhr = bhh[dir*384 + j];
    const float bhz = bhh[dir*384 + 128 + j];
    const float bhn = bhh[dir*384 + 256 + j];
    float4 w0r[8], w1r[8], w2r[8];
#pragma unroll
    for (int ii = 0; ii < 8; ++ii) {
        const int k4 = kq + (ii << 2);
        w0r[ii] = W[k4*384 + j];
        w1r[ii] = W[k4*384 + 128 + j];
        w2r[ii] = W[k4*384 + 256 + j];
    }

    for (int ts = 0; ts < 32; ++ts) {
        const int t = dir ? (31 - ts) : ts;
        float a0 = 0.f, a1 = 0.f, a2 = 0.f;
#pragma unroll
        for (int ii = 0; ii < 8; ++ii) {
            const int k4 = kq + (ii << 2);
            float4 w0 = w0r[ii];
            float4 w1 = w1r[ii];
            float4 w2 = w2r[ii];
            float4 h4 = *(const float4*)&h_lds[k4 << 2];
            a0 = fmaf(w0.x,h4.x, fmaf(w0.y,h4.y, fmaf(w0.z,h4.z, fmaf(w0.w,h4.w, a0))));
            a1 = fmaf(w1.x,h4.x, fmaf(w1.y,h4.y, fmaf(w1.z,h4.z, fmaf(w1.w,h4.w, a1))));
            a2 = fmaf(w2.x,h4.x, fmaf(w2.y,h4.y, fmaf(w2.z,h4.z, fmaf(w2.w,h4.w, a2))));
        }
        a0 += __shfl_xor(a0, 1); a0 += __shfl_xor(a0, 2);
        a1 += __shfl_xor(a1, 1); a1 += __shfl_xor(a1, 2);
        a2 += __shfl_xor(a2, 1); a2 += __shfl_xor(a2, 2);
        __syncthreads();
        if (kq == 0) {
            const float* xr = &xp_lds[t*XPLD];
            float r = sigmoidf_(xr[j]       + a0 + bhr);
            float z = sigmoidf_(xr[128 + j] + a1 + bhz);
            float nv = tanhf_(xr[256 + j] + r * (a2 + bhn));
            float hold = h_lds[j];
            float hnew = (1.f - z) * nv + z * hold;
            h_lds[j] = hnew;
            // packed hout: [row=doc*32+t][hilo2][k256] u16
            u16 hh, hl; bf16_split(hnew, hh, hl);
            const long base = ((long)(doc*32 + t)*2)*256 + dir*128 + j;
            houtp[base]       = hh;
            houtp[base + 256] = hl;
        }
        __syncthreads();
    }
}

extern "C" void kernel_launch(void* const* d_in, const int* in_sizes, int n_in,
                              void* d_out, int out_size, void* d_ws, size_t ws_size,
                              hipStream_t stream) {
    const int*   X       = (const int*)  d_in[0];
    const float* emb     = (const float*)d_in[1];
    const float* w_ih_f  = (const float*)d_in[2];
    const float* w_hh_f  = (const float*)d_in[3];
    const float* b_ih_f  = (const float*)d_in[4];
    const float* b_hh_f  = (const float*)d_in[5];
    const float* w_ih_b  = (const float*)d_in[6];
    const float* w_hh_b  = (const float*)d_in[7];
    const float* b_ih_b  = (const float*)d_in[8];
    const float* b_hh_b  = (const float*)d_in[9];
    const float* Ww      = (const float*)d_in[10];
    const float* bw      = (const float*)d_in[11];
    const float* ctx_w   = (const float*)d_in[12];
    const float* s_ih_f  = (const float*)d_in[13];
    const float* s_hh_f  = (const float*)d_in[14];
    const float* sb_ih_f = (const float*)d_in[15];
    const float* sb_hh_f = (const float*)d_in[16];
    const float* s_ih_b  = (const float*)d_in[17];
    const float* s_hh_b  = (const float*)d_in[18];
    const float* sb_ih_b = (const float*)d_in[19];
    const float* sb_hh_b = (const float*)d_in[20];
    const float* Ws      = (const float*)d_in[21];
    const float* bs      = (const float*)d_in[22];
    const float* ctx_s   = (const float*)d_in[23];
    const float* Wc      = (const float*)d_in[24];
    const float* bc      = (const float*)d_in[25];
    float* ws  = (float*)d_ws;
    float* out = (float*)d_out;

    if (ws_size < (size_t)WS_FLOATS * 4) return;   // fail cleanly if scratch too small

    // 1. weight prep
    prep_all<<<5260, 256, 0, stream>>>(s_ih_f, s_ih_b, w_ih_f, w_ih_b,
                                       w_hh_f, w_hh_b, s_hh_f, s_hh_b,
                                       b_ih_f, b_ih_b, sb_ih_f, sb_ih_b,
                                       b_hh_f, b_hh_b, sb_hh_f, sb_hh_b,
                                       Ww, Ws, ws);

    // 2. fused word pipeline
    gru_word_full<<<256, 768, 0, stream>>>(
        X, emb, (const u16*)(ws + OFF_WFX), (const u16*)(ws + OFF_WFHH),
        b_ih_f, b_ih_b, b_hh_f, b_hh_b, (u16*)(ws + OFF_HW));

    // 3. word attention -> sents (r30: 4 sentences/block, 1 dispatch round)
    attn_word4<<<256, 1024, 0, stream>>>(
        ws + OFF_HW, (const u16*)(ws + OFF_WFW_W), bw, ctx_w, ws + OFF_SENTS);

    // 4. sentence pipeline: xp MFMA + GRU -> packed u16 h
    gru_sent<<<64, 512, 0, stream>>>(
        ws + OFF_SENTS, (const u16*)(ws + OFF_W6), ws + OFF_BIH_S,
        (const float4*)(ws + OFF_W6) + 4*12288, ws + OFF_BHH_S, (u16*)(ws + OFF_HS));

    // 5. fused sentence attention + classifier -> logits
    attn_sent_cls<<<16, 1024, 0, stream>>>(
        (const u16*)(ws + OFF_HS), (const u16*)(ws + OFF_WFW_S), bs, ctx_s, out, Wc, bc);
}

// Round 17
// 299.033 us; speedup vs baseline: 1.0199x; 1.0199x over previous
//
#include <hip/hip_runtime.h>
#include <hip/hip_bf16.h>
#include <math.h>

// Problem constants
#define Bd 32
#define Sd 32
#define Ld 64
#define Ed 128
#define Hd 128
#define MW 65536   // B*S*L tokens
#define MS 1024    // B*S sentences

// ws layout (float offsets)
#define OFF_WFW_W    196608     // 131072 u16: word attn Ww B-frags hi/lo
#define OFF_WFW_S    262144     // 131072 u16: sent attn Ws B-frags hi/lo
#define OFF_W6       327680     // sets 0-3 region holds WFIHS frags (u16); sets 4,5: sentence GRU fp32
#define OFF_BIH_W    622592     // (unused, kept)
#define OFF_BIH_S    623360
#define OFF_BHH_W    624128     // (unused, kept)
#define OFF_BHH_S    624896
#define OFF_WFX      625664     // 196608 u16: word xp w_ih B-frags [dir][half][nt24][q4][l][e]
#define OFF_HW       723968     // 1024 sents x [t64][hilo2][k256] u16 = 33.5M u16
#define OFF_SENTS    17763328   // 1024 x 256
#define OFF_HS       18811904   // 1024 rows x [hilo2][k256] u16 (packed, r29)
#define OFF_WFHH     19086336   // 196608 u16: W_hh MFMA B-frags hi/lo
#define WS_FLOATS    19184640   // 76.7 MB

typedef __attribute__((ext_vector_type(8))) short sh8;
typedef __attribute__((ext_vector_type(4))) float f32x4;
typedef unsigned short u16;
typedef unsigned int u32;

#define GLD  388   // G stride, 8 rows (seqs 0-7, hi+lo pre-summed)
#define XPLD 385   // xp_lds stride (mod 32 = 1 -> banks spread)
#define HPLD 520   // h_pk per-q stride in u16 (q-pad spreads banks)

// Raw workgroup barrier: waits LDS/shfl (lgkmcnt) only, deliberately NOT vmcnt
// (in-flight global stores/gathers stay in flight across the barrier).
__device__ __forceinline__ void barrier_lds_only() {
    asm volatile("s_waitcnt lgkmcnt(0)\n\ts_barrier" ::: "memory");
}

__device__ __forceinline__ float sigmoidf_(float x) {
    return __fdividef(1.0f, 1.0f + __expf(-x));
}
__device__ __forceinline__ float tanhf_(float x) {
    float t = __expf(-2.0f * fabsf(x));
    float r = __fdividef(1.0f - t, 1.0f + t);
    return copysignf(r, x);
}
__device__ __forceinline__ u16 bf16_hi(float f) {
    u32 x = __float_as_uint(f);
    return (u16)((x + 0x7fffu + ((x >> 16) & 1u)) >> 16);
}
__device__ __forceinline__ float bf16_f(u16 u) { return __uint_as_float(((u32)u) << 16); }
__device__ __forceinline__ void bf16_split(float f, u16& hi, u16& lo) {
    hi = bf16_hi(f);
    lo = bf16_hi(f - bf16_f(hi));
}

// ---------------- fused weight prep (1 launch, 4 sections) ----------------
__global__ void prep_all(const float* __restrict__ s_ih_f, const float* __restrict__ s_ih_b,
                         const float* __restrict__ w_ih_f, const float* __restrict__ w_ih_b,
                         const float* __restrict__ w_hh_f, const float* __restrict__ w_hh_b,
                         const float* __restrict__ s_hh_f, const float* __restrict__ s_hh_b,
                         const float* __restrict__ b_ih_f, const float* __restrict__ b_ih_b,
                         const float* __restrict__ sb_ih_f, const float* __restrict__ sb_ih_b,
                         const float* __restrict__ b_hh_f, const float* __restrict__ b_hh_b,
                         const float* __restrict__ sb_hh_f, const float* __restrict__ sb_hh_b,
                         const float* __restrict__ Ww, const float* __restrict__ Ws,
                         float* __restrict__ ws)
{
    const int b = blockIdx.x;
    if (b < 1164) {
        int i = b * 256 + threadIdx.x;
        if (i < 294912) {  // W6 — only sets 4,5 live (sets 0-3 region = WFIHS, section D)
            int set = i / 49152;
            if (set < 4) return;
            int rem = i % 49152;
            int k4 = rem / 1536, r2 = rem % 1536, g = r2 >> 2, sub = r2 & 3;
            const float* w = (set==4) ? s_hh_f : s_hh_b;
            ws[OFF_W6 + i] = w[g*128 + k4*4 + sub];
            return;
        }
        i -= 294912;
        if (i < 768) { ws[OFF_BIH_W + i] = (i<384) ? b_ih_f[i] : b_ih_b[i-384]; return; }
        i -= 768;
        if (i < 768) { ws[OFF_BIH_S + i] = (i<384) ? sb_ih_f[i] : sb_ih_b[i-384]; return; }
        i -= 768;
        if (i < 768) { ws[OFF_BHH_W + i] = (i<384) ? b_hh_f[i] : b_hh_b[i-384]; return; }
        i -= 768;
        if (i < 768) { ws[OFF_BHH_S + i] = (i<384) ? sb_hh_f[i] : sb_hh_b[i-384]; return; }
        return;
    }
    if (b < 1932) {
        // ---- W_hh frags [dir2][half2][nt24][q4][lane64][elem8] ----
        u16* WFo = (u16*)(ws + OFF_WFHH);
        int i = (b - 1164) * 256 + threadIdx.x;   // < 196608
        int within = i % 49152;
        int combo  = i / 49152;      // dir*2 + half
        int half = combo & 1, dir = combo >> 1;
        int nt  = within / 2048;
        int r2  = within % 2048;
        int q   = r2 >> 9;
        int r3  = r2 & 511;
        int l   = r3 >> 3, e = r3 & 7;
        int n = nt*16 + (l & 15);
        int k = q*32 + ((l >> 4) << 3) + e;
        const float* src = dir ? w_hh_b : w_hh_f;
        float v = src[n*128 + k];
        u16 hi = bf16_hi(v);
        WFo[i] = half ? bf16_hi(v - bf16_f(hi)) : hi;
        return;
    }
    if (b < 3724) {
        // ---- attn (Ww,Ws) + word xp (w_ih) frags ----
        u16* WFW_W = (u16*)(ws + OFF_WFW_W);
        u16* WFW_S = (u16*)(ws + OFF_WFW_S);
        u16* WFX   = (u16*)(ws + OFF_WFX);
        int i = (b - 1932) * 256 + threadIdx.x;   // < 458752
        if (i < 262144) {
            int which = i / 131072;       // 0=Ww, 1=Ws
            int w = i % 131072;
            int half = w / 65536;
            int r = w % 65536;
            int nt = r / 4096;
            int r2 = r % 4096;
            int q = r2 / 512;
            int l = (r2 % 512) >> 3, e = r2 & 7;
            int n = nt*16 + (l & 15);
            int k = q*32 + ((l >> 4) << 3) + e;
            const float* src = which ? Ws : Ww;
            float v = src[n*256 + k];
            u16 hi = bf16_hi(v);
            u16 o = half ? bf16_hi(v - bf16_f(hi)) : hi;
            (which ? WFW_S : WFW_W)[w] = o;
            return;
        }
        i -= 262144;
        if (i < 196608) {
            int w = i % 98304;
            int dir = i / 98304;
            int half = w / 49152;
            int r = w % 49152;
            int nt = r / 2048;
            int r2 = r % 2048;
            int q = r2 / 512;
            int l = (r2 % 512) >> 3, e = r2 & 7;
            int n = nt*16 + (l & 15);
            int k = q*32 + ((l >> 4) << 3) + e;
            const float* src = dir ? w_ih_b : w_ih_f;
            float v = src[n*128 + k];
            u16 hi = bf16_hi(v);
            WFX[i] = half ? bf16_hi(v - bf16_f(hi)) : hi;
            return;
        }
        return;
    }
    {
        // ---- section D: WFIHS = s_ih B-frags [dir2][half2][nt24][q8][l64][e8] ----
        u16* WFIHS = (u16*)(ws + OFF_W6);
        int i = (b - 3724) * 256 + threadIdx.x;   // < 393216
        int dir  = i / 196608;
        int w    = i % 196608;
        int half = w / 98304;
        int r    = w % 98304;
        int nt = r / 4096;
        int r2 = r % 4096;
        int q  = r2 / 512;
        int l  = (r2 % 512) >> 3, e = r2 & 7;
        int n = nt*16 + (l & 15);                 // row in [0,384): gate*128 + j
        int k = q*32 + ((l >> 4) << 3) + e;       // k in [0,256)
        const float* src = dir ? s_ih_b : s_ih_f;
        float v = src[n*256 + k];
        u16 hi = bf16_hi(v);
        WFIHS[i] = half ? bf16_hi(v - bf16_f(hi)) : hi;
    }
}

// ---------------- fused word pipeline (r25 form; plateau ~194us) ----------
__global__ __launch_bounds__(768)
void gru_word_full(const int* __restrict__ X, const float* __restrict__ emb,
                   const u16* __restrict__ WFX, const u16* __restrict__ WFHH,
                   const float* __restrict__ b_ih_f, const float* __restrict__ b_ih_b,
                   const float* __restrict__ b_hh_f, const float* __restrict__ b_hh_b,
                   u16* __restrict__ houtp)
{
    const int bx = blockIdx.x;
    const int dir = bx >> 7;
    const int blk = bx & 127;
    const int seq0 = blk * 8;
    const int tid = threadIdx.x;
    const int lane = tid & 63;
    const int wid = tid >> 6;            // 0..11

    __shared__ float xp_lds[64 * XPLD];      // 98560 B (rows = s*8 + tt)
    __shared__ u16 a_pk[8 * 4 * 512];        // 32768 B
    __shared__ float G[8 * GLD];             // 12416 B (hi+lo pre-summed)
    __shared__ u16 h_pk[4 * HPLD];           // 4160 B (hi rows 0-7, lo rows 8-15)
    __shared__ int ids_s[8][64];             // 2048 B

    const int j = tid & 127;
    const int sg = tid >> 7;             // 0..3 gate threads (s = sg, sg+4)
    const bool gthread = tid < 512;
    const float* bih = dir ? b_ih_b : b_ih_f;
    const float* bhh = dir ? b_hh_b : b_hh_f;
    float bhr = 0.f, bhz = 0.f, bhn = 0.f;
    if (gthread) { bhr = bhh[j]; bhz = bhh[128 + j]; bhn = bhh[256 + j]; }

    const u16* WXbase = WFX + (long)dir * 98304;
    const u16* WHbase = WFHH + (long)dir * 98304;
    const int nt0 = wid*2, nt1 = wid*2 + 1;
    const int c0 = nt0*16 + (lane & 15);
    const int c1 = nt1*16 + (lane & 15);
    // gate-thread h_pk write decomposition for k = j
    const int qj = j >> 5, subkj = (j >> 3) & 3, ej = j & 7;

    for (int i = tid; i < 512; i += 768)
        ids_s[i >> 6][i & 63] = X[(long)(seq0 + (i >> 6))*64 + (i & 63)];
    for (int i = tid; i < 4*HPLD; i += 768) h_pk[i] = 0;
    __syncthreads();

    // prologue: stage chunk 0 with all 768 threads (float4 items)
    for (int idx = tid; idx < 2048; idx += 768) {
        int cc2 = idx & 1, rm = (idx >> 1) & 7, subk = (idx >> 4) & 3;
        int q = (idx >> 6) & 3, mfs = idx >> 8;
        int t = dir ? 63 - rm : rm;          // ts = 0*8 + rm
        int kk = q*32 + subk*8 + cc2*4;
        int id = ids_s[mfs][t];
        float4 v = make_float4(0.f, 0.f, 0.f, 0.f);
        if (id != 0) v = *(const float4*)&emb[(long)id*128 + kk];
        u16 h0,l0,h1,l1,h2,l2,h3,l3;
        bf16_split(v.x,h0,l0); bf16_split(v.y,h1,l1);
        bf16_split(v.z,h2,l2); bf16_split(v.w,h3,l3);
        int lh = subk*16 + rm;
        int base = (mfs*4 + q)*512 + lh*8 + cc2*4;
        uint2 whi = make_uint2((u32)h0 | ((u32)h1 << 16), (u32)h2 | ((u32)h3 << 16));
        uint2 wlo = make_uint2((u32)l0 | ((u32)l1 << 16), (u32)l2 | ((u32)l3 << 16));
        *(uint2*)&a_pk[base]      = whi;
        *(uint2*)&a_pk[base + 64] = wlo;
    }
    __syncthreads();

    float hprev0 = 0.f, hprev1 = 0.f;
    for (int c = 0; c < 8; ++c) {
        asm volatile("" ::: "memory");   // no cross-chunk hoisting of weight loads
        // ---- load W_ih frags (this chunk only) ----
        sh8 xh0[4], xl0[4], xh1[4], xl1[4];
#pragma unroll
        for (int q = 0; q < 4; ++q) {
            xh0[q] = *(const sh8*)(WXbase + (nt0*4 + q)*512 + lane*8);
            xl0[q] = *(const sh8*)(WXbase + 49152 + (nt0*4 + q)*512 + lane*8);
            xh1[q] = *(const sh8*)(WXbase + (nt1*4 + q)*512 + lane*8);
            xl1[q] = *(const sh8*)(WXbase + 49152 + (nt1*4 + q)*512 + lane*8);
        }
        const float bv0 = bih[c0], bv1 = bih[c1];
        // ---- xp MFMA (reads a_pk staged during chunk c-1's steps / prologue) ----
#pragma unroll
        for (int mf = 0; mf < 8; ++mf) {
            f32x4 A0 = (f32x4){0.f,0.f,0.f,0.f};
            f32x4 A1 = (f32x4){0.f,0.f,0.f,0.f};
#pragma unroll
            for (int q = 0; q < 4; ++q) {
                sh8 a = *(const sh8*)&a_pk[(mf*4 + q)*512 + lane*8];
                A0 = __builtin_amdgcn_mfma_f32_16x16x32_bf16(a, xh0[q], A0, 0,0,0);
                A0 = __builtin_amdgcn_mfma_f32_16x16x32_bf16(a, xl0[q], A0, 0,0,0);
                A1 = __builtin_amdgcn_mfma_f32_16x16x32_bf16(a, xh1[q], A1, 0,0,0);
                A1 = __builtin_amdgcn_mfma_f32_16x16x32_bf16(a, xl1[q], A1, 0,0,0);
            }
            float g0[4], g1[4];
#pragma unroll
            for (int r = 0; r < 4; ++r) {
                g0[r] = A0[r] + __shfl_xor(A0[r], 32);
                g1[r] = A1[r] + __shfl_xor(A1[r], 32);
            }
            if ((lane >= 32) == (mf & 1)) {
                int row = mf*8 + ((lane >> 4) & 1)*4;
#pragma unroll
                for (int r = 0; r < 4; ++r) {
                    xp_lds[(row+r)*XPLD + c0] = g0[r] + bv0;
                    xp_lds[(row+r)*XPLD + c1] = g1[r] + bv1;
                }
            }
        }
        barrier_lds_only();   // xp written; a_pk free for chunk c+1 restage
        asm volatile("" ::: "memory");
        // ---- load W_hh frags ----
        sh8 wh0[4], wl0[4], wh1[4], wl1[4];
#pragma unroll
        for (int q = 0; q < 4; ++q) {
            wh0[q] = *(const sh8*)(WHbase + (nt0*4 + q)*512 + lane*8);
            wl0[q] = *(const sh8*)(WHbase + 49152 + (nt0*4 + q)*512 + lane*8);
            wh1[q] = *(const sh8*)(WHbase + (nt1*4 + q)*512 + lane*8);
            wl1[q] = *(const sh8*)(WHbase + 49152 + (nt1*4 + q)*512 + lane*8);
        }
        // ---- 8 recurrence steps (+ chunk c+1 staging by waves 8-11) ----
        for (int tt = 0; tt < 8; ++tt) {
            const int ts = c*8 + tt;
            const int t = dir ? 63 - ts : ts;
            // stage-wave prefetch: issue the gather NOW; consume in the gate window
            float4 sv;
            int s_base = 0;
            const bool sv_ok = !gthread && (c < 7);
            if (sv_ok) {
                const int st = tid - 512;            // 0..255
                const int idx = tt*256 + st;
                int cc2 = idx & 1, rm = (idx >> 1) & 7, subk = (idx >> 4) & 3;
                int q = (idx >> 6) & 3, mfs = idx >> 8;
                int ts2 = (c+1)*8 + rm;
                int t2 = dir ? 63 - ts2 : ts2;
                int kk = q*32 + subk*8 + cc2*4;
                int id = ids_s[mfs][t2];
                sv = make_float4(0.f, 0.f, 0.f, 0.f);
                if (id != 0) sv = *(const float4*)&emb[(long)id*128 + kk];
                int lh = subk*16 + rm;
                s_base = (mfs*4 + q)*512 + lh*8 + cc2*4;
            }
            f32x4 acc0 = (f32x4){0.f,0.f,0.f,0.f};
            f32x4 acc1 = (f32x4){0.f,0.f,0.f,0.f};
#pragma unroll
            for (int q = 0; q < 4; ++q) {
                sh8 hp = *(const sh8*)&h_pk[q*HPLD + lane*8];
                acc0 = __builtin_amdgcn_mfma_f32_16x16x32_bf16(hp, wh0[q], acc0, 0,0,0);
                acc0 = __builtin_amdgcn_mfma_f32_16x16x32_bf16(hp, wl0[q], acc0, 0,0,0);
                acc1 = __builtin_amdgcn_mfma_f32_16x16x32_bf16(hp, wh1[q], acc1, 0,0,0);
                acc1 = __builtin_amdgcn_mfma_f32_16x16x32_bf16(hp, wl1[q], acc1, 0,0,0);
            }
            // summed-G: hi row s (lanes 0-31) + lo row s+8 (lanes 32-63) share a reg
            {
                float sg0[4], sg1[4];
#pragma unroll
                for (int r = 0; r < 4; ++r) {
                    sg0[r] = acc0[r] + __shfl_xor(acc0[r], 32);
                    sg1[r] = acc1[r] + __shfl_xor(acc1[r], 32);
                }
                if (lane < 32) {
                    const int col16 = lane & 15;
                    const int row0  = (lane >> 4) << 2;   // 0 or 4
#pragma unroll
                    for (int r = 0; r < 4; ++r) {
                        G[(row0+r)*GLD + nt0*16 + col16] = sg0[r];
                        G[(row0+r)*GLD + nt1*16 + col16] = sg1[r];
                    }
                }
            }
            barrier_lds_only();
            if (gthread) {
#pragma unroll
                for (int si = 0; si < 2; ++si) {
                    const int s = sg + si*4;
                    float gr  = G[s*GLD + j]       + bhr;
                    float gz  = G[s*GLD + 128 + j] + bhz;
                    float gnh = G[s*GLD + 256 + j] + bhn;
                    const float* xrow = &xp_lds[(s*8 + tt)*XPLD];
                    float r  = sigmoidf_(xrow[j] + gr);
                    float z  = sigmoidf_(xrow[128 + j] + gz);
                    float nv = tanhf_(xrow[256 + j] + r * gnh);
                    float hold = si ? hprev1 : hprev0;
                    float hnew = (1.f - z) * nv + z * hold;
                    if (si) hprev1 = hnew; else hprev0 = hnew;
                    u16 hh, hl; bf16_split(hnew, hh, hl);
                    // paired u32 writes: even j handles the hi row pair, odd j the lo
                    u16 ohh = (u16)__shfl_xor((int)hh, 1);
                    u16 ohl = (u16)__shfl_xor((int)hl, 1);
                    const long tbase = ((long)(seq0 + s)*64 + t)*512 + dir*128;
                    if ((j & 1) == 0) {
                        u32 w = (u32)hh | ((u32)ohh << 16);
                        *(u32*)&h_pk[qj*HPLD + (subkj*16 + s)*8 + ej] = w;
                        *(u32*)&houtp[tbase + j] = w;
                    } else {
                        u32 w = (u32)ohl | ((u32)hl << 16);
                        *(u32*)&h_pk[qj*HPLD + (subkj*16 + s + 8)*8 + (ej - 1)] = w;
                        *(u32*)&houtp[tbase + 256 + (j - 1)] = w;
                    }
                }
            } else if (sv_ok) {
                // stage-wave gate window: split the in-flight gather, store to a_pk
                u16 h0,l0,h1,l1,h2,l2,h3,l3;
                bf16_split(sv.x,h0,l0); bf16_split(sv.y,h1,l1);
                bf16_split(sv.z,h2,l2); bf16_split(sv.w,h3,l3);
                uint2 whi = make_uint2((u32)h0 | ((u32)h1 << 16), (u32)h2 | ((u32)h3 << 16));
                uint2 wlo = make_uint2((u32)l0 | ((u32)l1 << 16), (u32)l2 | ((u32)l3 << 16));
                *(uint2*)&a_pk[s_base]      = whi;
                *(uint2*)&a_pk[s_base + 64] = wlo;
            }
            barrier_lds_only();
        }
    }
}

// ---------------- word attention, 2 sentences/block (r28, proven best) -------------
__global__ __launch_bounds__(1024)
void attn_word2(const float* __restrict__ A, const u16* __restrict__ WF,
                const float* __restrict__ bias, const float* __restrict__ ctx,
                float* __restrict__ outp)
{
    __shared__ u16 a_pk[2][8][8][512];    // 131072 B
    __shared__ float pscore[2][8][8][17]; // 8704 B
    __shared__ float aw[128];             // 512 B
    __shared__ float red[8][256];         // 8192 B
    const int tid = threadIdx.x;
    const int lane = tid & 63;
    const int wid = tid >> 6;   // 0..15
    const int s0 = blockIdx.x * 2;

    sh8 bh[8], bl[8];
#pragma unroll
    for (int q = 0; q < 8; ++q) {
        bh[q] = *(const sh8*)(WF + (wid*8 + q)*512 + lane*8);
        bl[q] = *(const sh8*)(WF + 65536 + (wid*8 + q)*512 + lane*8);
    }
    const int colg = wid*16 + (lane & 15);
    const float bwv = bias[colg];
    const float cxv = ctx[colg];

    // uint4 staging, 2 sentences (8192 uint4 items)
    {
        const u32* src32 = (const u32*)A + (long)s0 * 16384;
        u32* dst = (u32*)a_pk;
        for (int idx4 = tid; idx4 < 8192; idx4 += 1024) {
            int sidx = idx4 >> 12;
            int idx  = (idx4 & 4095) << 2;
            int mf = idx >> 11, q = (idx >> 8) & 7, l = (idx >> 2) & 63;
            int row16 = l & 15, hilo = row16 >> 3, rm = row16 & 7;
            int t = mf*8 + rm;
            int kb2 = q*16 + (l >> 4)*4;       // (kbase>>1), multiple of 4
            *(uint4*)&dst[(sidx << 14) + idx] =
                *(const uint4*)&src32[(long)sidx*16384 + (t*2 + hilo)*128 + kb2];
        }
    }
    __syncthreads();

#pragma unroll 1
    for (int sidx = 0; sidx < 2; ++sidx) {
#pragma unroll
        for (int mf = 0; mf < 8; ++mf) {
            f32x4 acc = (f32x4){0.f,0.f,0.f,0.f};
#pragma unroll
            for (int q = 0; q < 8; ++q) {
                sh8 a = *(const sh8*)&a_pk[sidx][mf][q][lane*8];
                acc = __builtin_amdgcn_mfma_f32_16x16x32_bf16(a, bh[q], acc, 0,0,0);
                acc = __builtin_amdgcn_mfma_f32_16x16x32_bf16(a, bl[q], acc, 0,0,0);
            }
            float g[4];
#pragma unroll
            for (int r = 0; r < 4; ++r) g[r] = acc[r] + __shfl_xor(acc[r], 32);
            if ((lane >= 32) == (mf & 1)) {    // half-dedup: each half handles 4 mf
                float p[4];
#pragma unroll
                for (int r = 0; r < 4; ++r) p[r] = tanhf_(g[r] + bwv) * cxv;
#pragma unroll
                for (int r = 0; r < 4; ++r) {
                    p[r] += __shfl_xor(p[r], 1);
                    p[r] += __shfl_xor(p[r], 2);
                    p[r] += __shfl_xor(p[r], 4);
                    p[r] += __shfl_xor(p[r], 8);
                }
                if ((lane & 15) == 0) {
#pragma unroll
                    for (int r = 0; r < 4; ++r)
                        pscore[sidx][mf][((lane >> 4) & 1)*4 + r][wid] = p[r];
                }
            }
        }
    }
    __syncthreads();

    // softmax over 64 per sentence: wave 0 -> sent 0, wave 1 -> sent 1
    if (tid < 128) {
        const int sidx = tid >> 6, lt = tid & 63;
        float sc = 0.f;
#pragma unroll
        for (int w = 0; w < 16; ++w) sc += pscore[sidx][lt >> 3][lt & 7][w];
        float mx = sc;
#pragma unroll
        for (int m = 1; m < 64; m <<= 1) mx = fmaxf(mx, __shfl_xor(mx, m));
        float e = __expf(sc - mx);
        float den = e;
#pragma unroll
        for (int m = 1; m < 64; m <<= 1) den += __shfl_xor(den, m);
        aw[sidx*64 + lt] = __fdividef(e, den);
    }
    __syncthreads();

    // weighted sum: all 1024 threads; tg8 = (sentence, t-group)
    {
        const int tg8 = tid >> 7;          // 0..7
        const int sidx = tg8 >> 2;
        const int tg = tg8 & 3;
        const int dp = (tid & 127) << 1;
        const int q = dp >> 5, lhb = ((dp & 31) >> 3) << 4, e = dp & 7;
        float acc0 = 0.f, acc1 = 0.f;
#pragma unroll
        for (int ii = 0; ii < 16; ++ii) {
            int t = tg*16 + ii;
            int mf = t >> 3, rm = t & 7;
            const u16* base = &a_pk[sidx][mf][q][(lhb | rm)*8 + e];
            u32 hh = *(const u32*)base;
            u32 ll = *(const u32*)(base + 64);
            float h0 = bf16_f((u16)hh) + bf16_f((u16)ll);
            float h1 = bf16_f((u16)(hh >> 16)) + bf16_f((u16)(ll >> 16));
            float w = aw[sidx*64 + t];
            acc0 = fmaf(w, h0, acc0);
            acc1 = fmaf(w, h1, acc1);
        }
        red[tg8][dp] = acc0; red[tg8][dp + 1] = acc1;
    }
    __syncthreads();
    if (tid < 512) {
        const int sidx = tid >> 8, dd = tid & 255;
        outp[(long)(s0 + sidx)*256 + dd] =
            red[sidx*4 + 0][dd] + red[sidx*4 + 1][dd] + red[sidx*4 + 2][dd] + red[sidx*4 + 3][dd];
    }
}

// ---------------- sentence attention + classifier (r29 packed staging) -------------
__global__ __launch_bounds__(1024)
void attn_sent_cls(const u16* __restrict__ A, const u16* __restrict__ WF,
                   const float* __restrict__ bias, const float* __restrict__ ctx,
                   float* __restrict__ outp,
                   const float* __restrict__ Wc, const float* __restrict__ bc)
{
    __shared__ u16 a_pk[8][8][512];    // 64 KB
    __shared__ float pscore[8][8][17];
    __shared__ float aw[64];
    __shared__ float red[4][256];
    __shared__ float docv[2][256];
    const int tid = threadIdx.x;
    const int lane = tid & 63;
    const int wid = tid >> 6;   // 0..15

    sh8 bh[8], bl[8];
#pragma unroll
    for (int q = 0; q < 8; ++q) {
        bh[q] = *(const sh8*)(WF + (wid*8 + q)*512 + lane*8);
        bl[q] = *(const sh8*)(WF + 65536 + (wid*8 + q)*512 + lane*8);
    }
    const int colg = wid*16 + (lane & 15);
    const float bwv = bias[colg];
    const float cxv = ctx[colg];

    // uint4 packed staging (64 rows = 2 docs x 32 sents)
    {
        const u32* src32 = (const u32*)A + (long)blockIdx.x * 16384;
        u32* dst = (u32*)a_pk;
        for (int idx4 = tid; idx4 < 4096; idx4 += 1024) {
            int idx = idx4 << 2;
            int mf = idx >> 11, q = (idx >> 8) & 7, l = (idx >> 2) & 63;
            int row16 = l & 15, hilo = row16 >> 3, rm = row16 & 7;
            int t = mf*8 + rm;
            int kb2 = q*16 + (l >> 4)*4;
            *(uint4*)&dst[idx] = *(const uint4*)&src32[(t*2 + hilo)*128 + kb2];
        }
    }
    __syncthreads();

#pragma unroll
    for (int mf = 0; mf < 8; ++mf) {
        f32x4 acc = (f32x4){0.f,0.f,0.f,0.f};
#pragma unroll
        for (int q = 0; q < 8; ++q) {
            sh8 a = *(const sh8*)&a_pk[mf][q][lane*8];
            acc = __builtin_amdgcn_mfma_f32_16x16x32_bf16(a, bh[q], acc, 0,0,0);
            acc = __builtin_amdgcn_mfma_f32_16x16x32_bf16(a, bl[q], acc, 0,0,0);
        }
        float g[4];
#pragma unroll
        for (int r = 0; r < 4; ++r) g[r] = acc[r] + __shfl_xor(acc[r], 32);
        if ((lane >= 32) == (mf & 1)) {    // half-dedup
            float p[4];
#pragma unroll
            for (int r = 0; r < 4; ++r) p[r] = tanhf_(g[r] + bwv) * cxv;
#pragma unroll
            for (int r = 0; r < 4; ++r) {
                p[r] += __shfl_xor(p[r], 1);
                p[r] += __shfl_xor(p[r], 2);
                p[r] += __shfl_xor(p[r], 4);
                p[r] += __shfl_xor(p[r], 8);
            }
            if ((lane & 15) == 0) {
#pragma unroll
                for (int r = 0; r < 4; ++r)
                    pscore[mf][((lane >> 4) & 1)*4 + r][wid] = p[r];
            }
        }
    }
    __syncthreads();

    // softmax over 32 per sentence group in wave 0
    if (tid < 64) {
        float sc = 0.f;
#pragma unroll
        for (int w = 0; w < 16; ++w) sc += pscore[tid >> 3][tid & 7][w];
        float mx = sc;
#pragma unroll
        for (int m = 1; m < 32; m <<= 1) mx = fmaxf(mx, __shfl_xor(mx, m));
        float e = __expf(sc - mx);
        float den = e;
#pragma unroll
        for (int m = 1; m < 32; m <<= 1) den += __shfl_xor(den, m);
        aw[tid] = __fdividef(e, den);
    }
    __syncthreads();

    if (tid < 512) {
        const int dp = (tid & 127) << 1;
        const int tg = tid >> 7;          // 0..3
        const int q = dp >> 5, lhb = ((dp & 31) >> 3) << 4, e = dp & 7;
        float acc0 = 0.f, acc1 = 0.f;
#pragma unroll
        for (int ii = 0; ii < 16; ++ii) {
            int t = tg*16 + ii;
            int mf = t >> 3, rm = t & 7;
            const u16* base = &a_pk[mf][q][(lhb | rm)*8 + e];
            u32 hh = *(const u32*)base;
            u32 ll = *(const u32*)(base + 64);
            float h0 = bf16_f((u16)hh) + bf16_f((u16)ll);
            float h1 = bf16_f((u16)(hh >> 16)) + bf16_f((u16)(ll >> 16));
            float w = aw[t];
            acc0 = fmaf(w, h0, acc0);
            acc1 = fmaf(w, h1, acc1);
        }
        red[tg][dp] = acc0; red[tg][dp + 1] = acc1;
    }
    __syncthreads();
    // classifier fusion: docv -> logits
    if (tid < 512) {
        int sent = tid >> 8, dd = tid & 255;
        docv[sent][dd] = red[sent*2][dd] + red[sent*2 + 1][dd];
    }
    __syncthreads();
    if (tid < 20) {
        int s = tid / 10, c = tid % 10;
        float acc = bc[c];
        const float4* wp = (const float4*)&Wc[c*256];
        const float4* dv = (const float4*)&docv[s][0];
#pragma unroll 8
        for (int d = 0; d < 64; ++d) {
            float4 a = dv[d], w = wp[d];
            acc = fmaf(a.x, w.x, fmaf(a.y, w.y, fmaf(a.z, w.z, fmaf(a.w, w.w, acc))));
        }
        outp[(blockIdx.x*2 + s)*10 + c] = acc;
    }
}

// ---------------- sentence pipeline: xp MFMA + GRU -> packed u16 h (r29) -----------
__global__ __launch_bounds__(512)
void gru_sent(const float* __restrict__ sents, const u16* __restrict__ WFIHS,
              const float* __restrict__ bih_s, const float4* __restrict__ whh4,
              const float* __restrict__ bhh, u16* __restrict__ houtp)
{
    const int bx = blockIdx.x;
    const int dir = bx >> 5;
    const int doc = bx & 31;
    const int tid = threadIdx.x;
    const int lane = tid & 63;
    const int wid = tid >> 6;            // 0..7

    __shared__ float xp_lds[32 * XPLD];  // 49280 B
    __shared__ u16 a_pk[4 * 8 * 512];    // 32768 B: [mf4][q8][l64][e8]
    __shared__ float h_lds[128];

    for (int i = tid; i < 128; i += 512) h_lds[i] = 0.f;

    // ---- phase 1: stage sents rows -> A-frags ----
    for (int idx = tid; idx < 2048; idx += 512) {
        int cc2 = idx & 1, rm = (idx >> 1) & 7, subk = (idx >> 4) & 3;
        int q = (idx >> 6) & 7, mf = (idx >> 9) & 3;
        int t = mf*8 + rm;
        int kk = q*32 + subk*8 + cc2*4;
        float4 v = *(const float4*)&sents[(long)(doc*32 + t)*256 + kk];
        u16 h0,l0,h1,l1,h2,l2,h3,l3;
        bf16_split(v.x,h0,l0); bf16_split(v.y,h1,l1);
        bf16_split(v.z,h2,l2); bf16_split(v.w,h3,l3);
        int lh = subk*16 + rm;
        int base = (mf*8 + q)*512 + lh*8 + cc2*4;
        uint2 whi = make_uint2((u32)h0 | ((u32)h1 << 16), (u32)h2 | ((u32)h3 << 16));
        uint2 wlo = make_uint2((u32)l0 | ((u32)l1 << 16), (u32)l2 | ((u32)l3 << 16));
        *(uint2*)&a_pk[base]      = whi;
        *(uint2*)&a_pk[base + 64] = wlo;
    }
    barrier_lds_only();

    // ---- phase 2: xp MFMA, wave w -> nt {w, w+8, w+16} ----
    const u16* WFbase = WFIHS + (long)dir * 196608;
#pragma unroll 1
    for (int ni = 0; ni < 3; ++ni) {
        const int nt = wid + ni*8;
        sh8 wh[8], wl[8];
#pragma unroll
        for (int q = 0; q < 8; ++q) {
            wh[q] = *(const sh8*)(WFbase + (nt*8 + q)*512 + lane*8);
            wl[q] = *(const sh8*)(WFbase + 98304 + (nt*8 + q)*512 + lane*8);
        }
        const int col16 = lane & 15;
        const float bv = bih_s[dir*384 + nt*16 + col16];
        f32x4 A0 = (f32x4){0.f,0.f,0.f,0.f};
        f32x4 A1 = (f32x4){0.f,0.f,0.f,0.f};
        f32x4 A2 = (f32x4){0.f,0.f,0.f,0.f};
        f32x4 A3 = (f32x4){0.f,0.f,0.f,0.f};
#pragma unroll
        for (int q = 0; q < 8; ++q) {
            sh8 a0 = *(const sh8*)&a_pk[(0*8 + q)*512 + lane*8];
            sh8 a1 = *(const sh8*)&a_pk[(1*8 + q)*512 + lane*8];
            sh8 a2 = *(const sh8*)&a_pk[(2*8 + q)*512 + lane*8];
            sh8 a3 = *(const sh8*)&a_pk[(3*8 + q)*512 + lane*8];
            A0 = __builtin_amdgcn_mfma_f32_16x16x32_bf16(a0, wh[q], A0, 0,0,0);
            A0 = __builtin_amdgcn_mfma_f32_16x16x32_bf16(a0, wl[q], A0, 0,0,0);
            A1 = __builtin_amdgcn_mfma_f32_16x16x32_bf16(a1, wh[q], A1, 0,0,0);
            A1 = __builtin_amdgcn_mfma_f32_16x16x32_bf16(a1, wl[q], A1, 0,0,0);
            A2 = __builtin_amdgcn_mfma_f32_16x16x32_bf16(a2, wh[q], A2, 0,0,0);
            A2 = __builtin_amdgcn_mfma_f32_16x16x32_bf16(a2, wl[q], A2, 0,0,0);
            A3 = __builtin_amdgcn_mfma_f32_16x16x32_bf16(a3, wh[q], A3, 0,0,0);
            A3 = __builtin_amdgcn_mfma_f32_16x16x32_bf16(a3, wl[q], A3, 0,0,0);
        }
#pragma unroll
        for (int mf = 0; mf < 4; ++mf) {
            f32x4 A = (mf==0) ? A0 : (mf==1) ? A1 : (mf==2) ? A2 : A3;
            float g[4];
#pragma unroll
            for (int r = 0; r < 4; ++r) g[r] = A[r] + __shfl_xor(A[r], 32);
            if ((lane >= 32) == (mf & 1)) {
                int row = mf*8 + ((lane >> 4) & 1)*4;
#pragma unroll
                for (int r = 0; r < 4; ++r)
                    xp_lds[(row+r)*XPLD + nt*16 + col16] = g[r] + bv;
            }
        }
    }
    barrier_lds_only();
    asm volatile("" ::: "memory");   // keep recurrence weight loads below xp phase

    // ---- phase 3: recurrence (full hoisted weights; xp from LDS) ----
    const int kq = tid & 3;
    const int j  = tid >> 2;
    const float4* W = whh4 + (long)dir * 12288;
    const float bhr = bhh[dir*384 + j];
    const float bhz = bhh[dir*384 + 128 + j];
    const float bhn = bhh[dir*384 + 256 + j];
    float4 w0r[8], w1r[8], w2r[8];
#pragma unroll
    for (int ii = 0; ii < 8; ++ii) {
        const int k4 = kq + (ii << 2);
        w0r[ii] = W[k4*384 + j];
        w1r[ii] = W[k4*384 + 128 + j];
        w2r[ii] = W[k4*384 + 256 + j];
    }

    for (int ts = 0; ts < 32; ++ts) {
        const int t = dir ? (31 - ts) : ts;
        float a0 = 0.f, a1 = 0.f, a2 = 0.f;
#pragma unroll
        for (int ii = 0; ii < 8; ++ii) {
            const int k4 = kq + (ii << 2);
            float4 w0 = w0r[ii];
            float4 w1 = w1r[ii];
            float4 w2 = w2r[ii];
            float4 h4 = *(const float4*)&h_lds[k4 << 2];
            a0 = fmaf(w0.x,h4.x, fmaf(w0.y,h4.y, fmaf(w0.z,h4.z, fmaf(w0.w,h4.w, a0))));
            a1 = fmaf(w1.x,h4.x, fmaf(w1.y,h4.y, fmaf(w1.z,h4.z, fmaf(w1.w,h4.w, a1))));
            a2 = fmaf(w2.x,h4.x, fmaf(w2.y,h4.y, fmaf(w2.z,h4.z, fmaf(w2.w,h4.w, a2))));
        }
        a0 += __shfl_xor(a0, 1); a0 += __shfl_xor(a0, 2);
        a1 += __shfl_xor(a1, 1); a1 += __shfl_xor(a1, 2);
        a2 += __shfl_xor(a2, 1); a2 += __shfl_xor(a2, 2);
        __syncthreads();
        if (kq == 0) {
            const float* xr = &xp_lds[t*XPLD];
            float r = sigmoidf_(xr[j]       + a0 + bhr);
            float z = sigmoidf_(xr[128 + j] + a1 + bhz);
            float nv = tanhf_(xr[256 + j] + r * (a2 + bhn));
            float hold = h_lds[j];
            float hnew = (1.f - z) * nv + z * hold;
            h_lds[j] = hnew;
            // packed hout: [row=doc*32+t][hilo2][k256] u16
            u16 hh, hl; bf16_split(hnew, hh, hl);
            const long base = ((long)(doc*32 + t)*2)*256 + dir*128 + j;
            houtp[base]       = hh;
            houtp[base + 256] = hl;
        }
        __syncthreads();
    }
}

extern "C" void kernel_launch(void* const* d_in, const int* in_sizes, int n_in,
                              void* d_out, int out_size, void* d_ws, size_t ws_size,
                              hipStream_t stream) {
    const int*   X       = (const int*)  d_in[0];
    const float* emb     = (const float*)d_in[1];
    const float* w_ih_f  = (const float*)d_in[2];
    const float* w_hh_f  = (const float*)d_in[3];
    const float* b_ih_f  = (const float*)d_in[4];
    const float* b_hh_f  = (const float*)d_in[5];
    const float* w_ih_b  = (const float*)d_in[6];
    const float* w_hh_b  = (const float*)d_in[7];
    const float* b_ih_b  = (const float*)d_in[8];
    const float* b_hh_b  = (const float*)d_in[9];
    const float* Ww      = (const float*)d_in[10];
    const float* bw      = (const float*)d_in[11];
    const float* ctx_w   = (const float*)d_in[12];
    const float* s_ih_f  = (const float*)d_in[13];
    const float* s_hh_f  = (const float*)d_in[14];
    const float* sb_ih_f = (const float*)d_in[15];
    const float* sb_hh_f = (const float*)d_in[16];
    const float* s_ih_b  = (const float*)d_in[17];
    const float* s_hh_b  = (const float*)d_in[18];
    const float* sb_ih_b = (const float*)d_in[19];
    const float* sb_hh_b = (const float*)d_in[20];
    const float* Ws      = (const float*)d_in[21];
    const float* bs      = (const float*)d_in[22];
    const float* ctx_s   = (const float*)d_in[23];
    const float* Wc      = (const float*)d_in[24];
    const float* bc      = (const float*)d_in[25];
    float* ws  = (float*)d_ws;
    float* out = (float*)d_out;

    if (ws_size < (size_t)WS_FLOATS * 4) return;   // fail cleanly if scratch too small

    // 1. weight prep
    prep_all<<<5260, 256, 0, stream>>>(s_ih_f, s_ih_b, w_ih_f, w_ih_b,
                                       w_hh_f, w_hh_b, s_hh_f, s_hh_b,
                                       b_ih_f, b_ih_b, sb_ih_f, sb_ih_b,
                                       b_hh_f, b_hh_b, sb_hh_f, sb_hh_b,
                                       Ww, Ws, ws);

    // 2. fused word pipeline
    gru_word_full<<<256, 768, 0, stream>>>(
        X, emb, (const u16*)(ws + OFF_WFX), (const u16*)(ws + OFF_WFHH),
        b_ih_f, b_ih_b, b_hh_f, b_hh_b, (u16*)(ws + OFF_HW));

    // 3. word attention -> sents (2 sentences/block, best measured config)
    attn_word2<<<512, 1024, 0, stream>>>(
        ws + OFF_HW, (const u16*)(ws + OFF_WFW_W), bw, ctx_w, ws + OFF_SENTS);

    // 4. sentence pipeline: xp MFMA + GRU -> packed u16 h
    gru_sent<<<64, 512, 0, stream>>>(
        ws + OFF_SENTS, (const u16*)(ws + OFF_W6), ws + OFF_BIH_S,
        (const float4*)(ws + OFF_W6) + 4*12288, ws + OFF_BHH_S, (u16*)(ws + OFF_HS));

    // 5. fused sentence attention + classifier -> logits
    attn_sent_cls<<<16, 1024, 0, stream>>>(
        (const u16*)(ws + OFF_HS), (const u16*)(ws + OFF_WFW_S), bs, ctx_s, out, Wc, bc);
}